// Round 6
// baseline (277.841 us; speedup 1.0000x reference)
//
#include <hip/hip_runtime.h>
#include <stdint.h>

#define NODES 16384
#define D0    263
#define K1PAD 288
#define OUTW  1031   // 263 + 256*3

typedef __attribute__((ext_vector_type(8))) short bf16x8;
typedef __attribute__((ext_vector_type(4))) float f32x4;
typedef __attribute__((ext_vector_type(4))) unsigned short u16x4;

__device__ __forceinline__ float bf2f(unsigned short u) {
    union { unsigned int i; float f; } c; c.i = ((unsigned int)u) << 16; return c.f;
}
__device__ __forceinline__ unsigned short f2bf(float f) {
    union { float f; unsigned int i; } c; c.f = f;
    unsigned int x = c.i;
    unsigned int r = (x + 0x7fffu + ((x >> 16) & 1u)) >> 16;
    return (unsigned short)r;
}
// order-preserving bf16 -> u16 key (unsigned max == float max)
__device__ __forceinline__ unsigned short bf2key(unsigned short b) {
    return (b & 0x8000u) ? (unsigned short)~b : (unsigned short)(b | 0x8000u);
}
__device__ __forceinline__ unsigned short key2bf(unsigned short k) {
    return (k & 0x8000u) ? (unsigned short)(k ^ 0x8000u) : (unsigned short)~k;
}

// ------------------------------------------------- detect dtypes + zero deg
// flags[0]: edge_index is int64 ; flags[1]: floats are f32
__global__ void detect_zero_kernel(const void* __restrict__ ei, const void* __restrict__ pooled,
                                   int* __restrict__ flags, int* __restrict__ deg) {
    int idx = blockIdx.x * 256 + threadIdx.x;
    deg[idx] = 0;
    if (blockIdx.x == 0 && threadIdx.x < 64) {
        int lane = threadIdx.x;
        const long long* e64 = (const long long*)ei;
        bool ok = true;
        for (int i = lane; i < 512; i += 64) {
            long long v = e64[i];
            if (v < 0 || v >= NODES) ok = false;
        }
        unsigned long long b = __ballot(ok);
        const unsigned short* ph = (const unsigned short*)pooled;
        int hits = 0;
        for (int i = lane; i < 512; i += 64) {
            int e = (ph[i] >> 7) & 0xFF;
            if (e >= 0x90) hits++;   // |v| >= 2^17: impossible for N(0,1) bf16 data
        }
        for (int off = 32; off; off >>= 1) hits += __shfl_down(hits, off);
        if (lane == 0) {
            flags[0] = (b == ~0ull) ? 1 : 0;
            flags[1] = (hits > 8) ? 1 : 0;
        }
    }
}

// ---------------------------------------------------------------- edge sort
__global__ void hist_kernel(const void* __restrict__ ei, int E, const int* __restrict__ flags,
                            int* __restrict__ deg) {
    int e = blockIdx.x * blockDim.x + threadIdx.x;
    if (e >= E) return;
    int d = flags[0] ? (int)((const long long*)ei)[(size_t)E + e]
                     : ((const int*)ei)[(size_t)E + e];
    atomicAdd(&deg[d], 1);
}

__global__ void scan_kernel(const int* __restrict__ deg, int* __restrict__ offs,
                            int* __restrict__ cursor) {
    __shared__ int part[256];
    int tid = threadIdx.x;
    int base = tid * 64;
    int s = 0;
    for (int i = 0; i < 64; ++i) s += deg[base + i];
    part[tid] = s;
    __syncthreads();
    for (int off = 1; off < 256; off <<= 1) {
        int t = (tid >= off) ? part[tid - off] : 0;
        __syncthreads();
        part[tid] += t;
        __syncthreads();
    }
    int run = (tid > 0) ? part[tid - 1] : 0;
    for (int i = 0; i < 64; ++i) {
        int idx = base + i;
        offs[idx] = run;
        cursor[idx] = run;
        run += deg[idx];
    }
    if (tid == 255) offs[NODES] = run;
}

__global__ void scatter_kernel(const void* __restrict__ ei, int E, const int* __restrict__ flags,
                               int* __restrict__ cursor, int* __restrict__ ssrc) {
    int e = blockIdx.x * blockDim.x + threadIdx.x;
    if (e >= E) return;
    int s, d;
    if (flags[0]) {
        const long long* p = (const long long*)ei;
        s = (int)p[e];
        d = (int)p[(size_t)E + e];
    } else {
        const int* p = (const int*)ei;
        s = p[e];
        d = p[(size_t)E + e];
    }
    int pos = atomicAdd(&cursor[d], 1);
    ssrc[pos] = s;
}

// ------------------------------------------- x0 staging + weight prep fused
#define T0 (NODES * K1PAD)
#define S1 (512 * K1PAD)
#define S2 (512 * 256)
__global__ void setup_kernel(const void* __restrict__ pooled, const void* __restrict__ rois,
                             const void* __restrict__ W1, const void* __restrict__ W2,
                             const void* __restrict__ W3, const int* __restrict__ flags,
                             unsigned short* __restrict__ x0p, void* __restrict__ outv,
                             unsigned short* __restrict__ wc1, unsigned short* __restrict__ wc2,
                             unsigned short* __restrict__ wc3) {
    int idx = blockIdx.x * 256 + threadIdx.x;
    bool f32m = flags[1] != 0;
    if (idx < T0) {
        int node = idx / K1PAD;
        int k = idx - node * K1PAD;
        float val = 0.f;
        if (k < 256) {
            val = f32m ? ((const float*)pooled)[(size_t)node * 256 + k]
                       : bf2f(((const unsigned short*)pooled)[(size_t)node * 256 + k]);
        } else if (k < D0) {
            val = f32m ? ((const float*)rois)[(size_t)node * 7 + (k - 256)]
                       : bf2f(((const unsigned short*)rois)[(size_t)node * 7 + (k - 256)]);
        }
        x0p[idx] = f2bf(val);
        if (k < D0) {
            if (f32m) ((float*)outv)[(size_t)node * OUTW + k] = val;
            else      ((unsigned short*)outv)[(size_t)node * OUTW + k] = f2bf(val);
        }
        return;
    }
    idx -= T0;
    if (idx < S1) {
        // layer 1: W1 is [256][526], in=263 padded to 288
        int r = idx / K1PAD;
        int k = idx - r * K1PAD;
        unsigned short val = 0;
        if (k < D0) {
            if (r < 256) {
                float a = f32m ? ((const float*)W1)[(size_t)r * 526 + k]
                               : bf2f(((const unsigned short*)W1)[(size_t)r * 526 + k]);
                val = f2bf(a);
            } else {
                size_t ro = (size_t)(r - 256) * 526;
                float a, b;
                if (f32m) { a = ((const float*)W1)[ro + k]; b = ((const float*)W1)[ro + D0 + k]; }
                else      { a = bf2f(((const unsigned short*)W1)[ro + k]);
                            b = bf2f(((const unsigned short*)W1)[ro + D0 + k]); }
                val = f2bf(b - a);
            }
        }
        wc1[idx] = val;
        return;
    }
    idx -= S1;
    const void* W = (idx < S2) ? W2 : W3;
    unsigned short* wc = (idx < S2) ? wc2 : wc3;
    if (idx >= S2) idx -= S2;
    int r = idx >> 8;
    int k = idx & 255;
    unsigned short val;
    if (r < 256) {
        float a = f32m ? ((const float*)W)[(size_t)r * 512 + k]
                       : bf2f(((const unsigned short*)W)[(size_t)r * 512 + k]);
        val = f2bf(a);
    } else {
        size_t ro = (size_t)(r - 256) * 512;
        float a, b;
        if (f32m) { a = ((const float*)W)[ro + k]; b = ((const float*)W)[ro + 256 + k]; }
        else      { a = bf2f(((const unsigned short*)W)[ro + k]);
                    b = bf2f(((const unsigned short*)W)[ro + 256 + k]); }
        val = f2bf(b - a);
    }
    wc[idx] = val;
}

// ---------------------------------------------------------------- GEMM
// T[M,512] = A[M,K]*Wc[512,K]^T ; cols 0..127 -> u_lo keys, 128..255 -> u_hi keys,
// 256..511 -> v (f32). wave = 64x64 (acc[4][4]); block 64x256; grid (M/64,2).
template <int K>
__global__ __launch_bounds__(256) void gemm_kernel(const unsigned short* __restrict__ A,
                                                   const unsigned short* __restrict__ Wc,
                                                   unsigned short* __restrict__ u_lo,
                                                   unsigned short* __restrict__ u_hi,
                                                   float* __restrict__ v_f) {
    int lane = threadIdx.x & 63;
    int wave = threadIdx.x >> 6;
    int row0 = blockIdx.x * 64;
    int col0 = blockIdx.y * 256 + wave * 64;
    int lr = lane & 15;
    int kb = (lane >> 4) * 8;
    const unsigned short* Ap = A + (size_t)(row0 + lr) * K + kb;
    const unsigned short* Wp = Wc + (size_t)(col0 + lr) * K + kb;

    f32x4 acc[4][4];
    #pragma unroll
    for (int i = 0; i < 4; ++i)
        #pragma unroll
        for (int j = 0; j < 4; ++j) acc[i][j] = (f32x4){0.f, 0.f, 0.f, 0.f};

    for (int k0 = 0; k0 < K; k0 += 32) {
        bf16x8 a[4], b[4];
        #pragma unroll
        for (int i = 0; i < 4; ++i) a[i] = *reinterpret_cast<const bf16x8*>(Ap + (size_t)i * 16 * K + k0);
        #pragma unroll
        for (int i = 0; i < 4; ++i) b[i] = *reinterpret_cast<const bf16x8*>(Wp + (size_t)i * 16 * K + k0);
        #pragma unroll
        for (int rb = 0; rb < 4; ++rb)
            #pragma unroll
            for (int cb = 0; cb < 4; ++cb)
                acc[rb][cb] = __builtin_amdgcn_mfma_f32_16x16x32_bf16(a[rb], b[cb], acc[rb][cb], 0, 0, 0);
    }

    bool is_u = (blockIdx.y == 0);
    #pragma unroll
    for (int rb = 0; rb < 4; ++rb) {
        int rbase = row0 + rb * 16 + (lane >> 4) * 4;
        #pragma unroll
        for (int cb = 0; cb < 4; ++cb) {
            int c = col0 + cb * 16 + lr;
            #pragma unroll
            for (int reg = 0; reg < 4; ++reg) {
                float val = acc[rb][cb][reg];
                int r = rbase + reg;
                if (is_u) {
                    unsigned short key = bf2key(f2bf(val));
                    if (c < 128) u_lo[(size_t)r * 128 + c] = key;
                    else         u_hi[(size_t)r * 128 + (c - 128)] = key;
                } else {
                    v_f[(size_t)r * 256 + (c - 256)] = val;
                }
            }
        }
    }
}

// ---------------------------------------------------------------- combine
// One wave per node, 128 channels (one 4MB u half -> per-XCD-L2-resident
// target). Two 32-lane halves own alternate sorted rows; u16x4 loads, 4 rows/
// half in flight, packed v_pk_max_u16; cross-half shfl_xor merge.
__global__ __launch_bounds__(256) void combine_kernel(const unsigned short* __restrict__ U,
                                                      const float* __restrict__ v_f,
                                                      const void* __restrict__ bias,
                                                      const int* __restrict__ flags,
                                                      const int* __restrict__ offs,
                                                      const int* __restrict__ ssrc,
                                                      unsigned short* __restrict__ x_cur,
                                                      void* __restrict__ outv,
                                                      int col_off,   // D0 + layer*256 + ch_off
                                                      int ch_off) {
    int lane = threadIdx.x & 63;
    int node = blockIdx.x * 4 + (threadIdx.x >> 6);
    int half = lane >> 5;      // 0/1: alternate rows
    int cl = lane & 31;        // channel-lane: ch cl*4 .. cl*4+3
    int s0 = offs[node];
    int s1 = offs[node + 1];
    bool f32m = flags[1] != 0;

    const u16x4* U4 = (const u16x4*)U;   // one row = 32 u16x4 (128 ch)
    u16x4 mk = (u16x4)0;

    int i = s0 + half;
    for (; i + 6 < s1; i += 8) {
        int sA = ssrc[i], sB = ssrc[i + 2], sC = ssrc[i + 4], sD = ssrc[i + 6];
        u16x4 pA = U4[(size_t)sA * 32 + cl];
        u16x4 pB = U4[(size_t)sB * 32 + cl];
        u16x4 pC = U4[(size_t)sC * 32 + cl];
        u16x4 pD = U4[(size_t)sD * 32 + cl];
        mk = __builtin_elementwise_max(mk, __builtin_elementwise_max(
                 __builtin_elementwise_max(pA, pB), __builtin_elementwise_max(pC, pD)));
    }
    for (; i < s1; i += 2) {
        int s = ssrc[i];
        mk = __builtin_elementwise_max(mk, U4[(size_t)s * 32 + cl]);
    }

    // merge halves: lanes l and l^32 hold the same 4 channels
    union { u16x4 v; uint2 u; } c1;
    c1.v = mk;
    c1.u.x = __shfl_xor((int)c1.u.x, 32);
    c1.u.y = __shfl_xor((int)c1.u.y, 32);
    mk = __builtin_elementwise_max(mk, c1.v);

    // epilogue: lane handles 2 channels: ch0 = cl*4 + half*2 (within the half)
    int ch0 = cl * 4 + half * 2;
    float m0 = bf2f(key2bf(mk[half * 2 + 0]));
    float m1 = bf2f(key2bf(mk[half * 2 + 1]));
    float2 v = *(const float2*)(v_f + (size_t)node * 256 + ch_off + ch0);
    float b0, b1;
    if (f32m) {
        const float* bf = (const float*)bias;
        b0 = bf[ch_off + ch0]; b1 = bf[ch_off + ch0 + 1];
    } else {
        const unsigned short* bh = (const unsigned short*)bias;
        b0 = bf2f(bh[ch_off + ch0]); b1 = bf2f(bh[ch_off + ch0 + 1]);
    }
    bool nz = (s1 > s0);
    float r0 = nz ? fmaxf(m0 + v.x + b0, 0.f) : 0.f;
    float r1 = nz ? fmaxf(m1 + v.y + b1, 0.f) : 0.f;

    unsigned short h0 = f2bf(r0), h1 = f2bf(r1);
    unsigned int hp = (unsigned int)h0 | ((unsigned int)h1 << 16);
    *(unsigned int*)(x_cur + (size_t)node * 256 + ch_off + ch0) = hp;

    size_t ob = (size_t)node * OUTW + col_off + ch0;
    if (f32m) {
        float* of = (float*)outv;
        of[ob + 0] = r0; of[ob + 1] = r1;
    } else {
        unsigned short* oh = (unsigned short*)outv;
        oh[ob + 0] = h0; oh[ob + 1] = h1;
    }
}

// ---------------------------------------------------------------- launch
extern "C" void kernel_launch(void* const* d_in, const int* in_sizes, int n_in,
                              void* d_out, int out_size, void* d_ws, size_t ws_size,
                              hipStream_t stream) {
    const void* rois   = d_in[0];
    const void* pooled = d_in[1];
    const void* ei     = d_in[2];
    const void* W1 = d_in[3];
    const void* b1 = d_in[4];
    const void* W2 = d_in[5];
    const void* b2 = d_in[6];
    const void* W3 = d_in[7];
    const void* b3 = d_in[8];

    const int E = in_sizes[2] / 2;

    char* ws = (char*)d_ws;
    size_t o = 0;
    auto take = [&](size_t bytes) { size_t cur = o; o += (bytes + 255) & ~(size_t)255; return cur; };
    int* flags           = (int*)(ws + take(8));
    int* deg             = (int*)(ws + take(sizeof(int) * NODES));
    int* offs            = (int*)(ws + take(sizeof(int) * (NODES + 1)));
    int* cursor          = (int*)(ws + take(sizeof(int) * NODES));
    int* ssrc            = (int*)(ws + take(sizeof(int) * (size_t)E));
    unsigned short* x0p  = (unsigned short*)(ws + take(2ull * NODES * K1PAD));
    unsigned short* wc1  = (unsigned short*)(ws + take(2ull * 512 * K1PAD));
    unsigned short* wc2  = (unsigned short*)(ws + take(2ull * 512 * 256));
    unsigned short* wc3  = (unsigned short*)(ws + take(2ull * 512 * 256));
    unsigned short* u_lo = (unsigned short*)(ws + take(2ull * NODES * 128));
    unsigned short* u_hi = (unsigned short*)(ws + take(2ull * NODES * 128));
    float*          vf   = (float*)(ws + take(4ull * NODES * 256));
    unsigned short* xcur = (unsigned short*)(ws + take(2ull * NODES * 256));
    (void)ws_size;

    const int eb = (E + 255) / 256;

    detect_zero_kernel<<<NODES / 256, 256, 0, stream>>>(ei, pooled, flags, deg);
    hist_kernel<<<eb, 256, 0, stream>>>(ei, E, flags, deg);
    scan_kernel<<<1, 256, 0, stream>>>(deg, offs, cursor);
    scatter_kernel<<<eb, 256, 0, stream>>>(ei, E, flags, cursor, ssrc);

    setup_kernel<<<(T0 + S1 + 2 * S2) / 256, 256, 0, stream>>>(pooled, rois, W1, W2, W3, flags,
                                                               x0p, d_out, wc1, wc2, wc3);

    // layer 1
    gemm_kernel<K1PAD><<<dim3(NODES / 64, 2), 256, 0, stream>>>(x0p, wc1, u_lo, u_hi, vf);
    combine_kernel<<<NODES / 4, 256, 0, stream>>>(u_lo, vf, b1, flags, offs, ssrc, xcur, d_out, D0, 0);
    combine_kernel<<<NODES / 4, 256, 0, stream>>>(u_hi, vf, b1, flags, offs, ssrc, xcur, d_out, D0 + 128, 128);

    // layer 2
    gemm_kernel<256><<<dim3(NODES / 64, 2), 256, 0, stream>>>(xcur, wc2, u_lo, u_hi, vf);
    combine_kernel<<<NODES / 4, 256, 0, stream>>>(u_lo, vf, b2, flags, offs, ssrc, xcur, d_out, D0 + 256, 0);
    combine_kernel<<<NODES / 4, 256, 0, stream>>>(u_hi, vf, b2, flags, offs, ssrc, xcur, d_out, D0 + 384, 128);

    // layer 3
    gemm_kernel<256><<<dim3(NODES / 64, 2), 256, 0, stream>>>(xcur, wc3, u_lo, u_hi, vf);
    combine_kernel<<<NODES / 4, 256, 0, stream>>>(u_lo, vf, b3, flags, offs, ssrc, xcur, d_out, D0 + 512, 0);
    combine_kernel<<<NODES / 4, 256, 0, stream>>>(u_hi, vf, b3, flags, offs, ssrc, xcur, d_out, D0 + 640, 128);
}

// Round 8
// 260.942 us; speedup vs baseline: 1.0648x; 1.0648x over previous
//
#include <hip/hip_runtime.h>
#include <stdint.h>

#define NODES 16384
#define D0    263
#define K1PAD 288
#define OUTW  1031   // 263 + 256*3

typedef __attribute__((ext_vector_type(8))) short bf16x8;
typedef __attribute__((ext_vector_type(4))) float f32x4;
typedef __attribute__((ext_vector_type(8))) unsigned short u16x8;

__device__ __forceinline__ float bf2f(unsigned short u) {
    union { unsigned int i; float f; } c; c.i = ((unsigned int)u) << 16; return c.f;
}
__device__ __forceinline__ unsigned short f2bf(float f) {
    union { float f; unsigned int i; } c; c.f = f;
    unsigned int x = c.i;
    unsigned int r = (x + 0x7fffu + ((x >> 16) & 1u)) >> 16;
    return (unsigned short)r;
}
// order-preserving bf16 -> u16 key (unsigned max == float max)
__device__ __forceinline__ unsigned short bf2key(unsigned short b) {
    return (b & 0x8000u) ? (unsigned short)~b : (unsigned short)(b | 0x8000u);
}
__device__ __forceinline__ unsigned short key2bf(unsigned short k) {
    return (k & 0x8000u) ? (unsigned short)(k ^ 0x8000u) : (unsigned short)~k;
}

// ------------------------------------------------- detect dtypes + zero deg
// flags[0]: edge_index is int64 ; flags[1]: floats are f32
__global__ void detect_zero_kernel(const void* __restrict__ ei, const void* __restrict__ pooled,
                                   int* __restrict__ flags, int* __restrict__ deg) {
    int idx = blockIdx.x * 256 + threadIdx.x;
    deg[idx] = 0;
    if (blockIdx.x == 0 && threadIdx.x < 64) {
        int lane = threadIdx.x;
        const long long* e64 = (const long long*)ei;
        bool ok = true;
        for (int i = lane; i < 512; i += 64) {
            long long v = e64[i];
            if (v < 0 || v >= NODES) ok = false;
        }
        unsigned long long b = __ballot(ok);
        const unsigned short* ph = (const unsigned short*)pooled;
        int hits = 0;
        for (int i = lane; i < 512; i += 64) {
            int e = (ph[i] >> 7) & 0xFF;
            if (e >= 0x90) hits++;   // |v| >= 2^17: impossible for N(0,1) bf16 data
        }
        for (int off = 32; off; off >>= 1) hits += __shfl_down(hits, off);
        if (lane == 0) {
            flags[0] = (b == ~0ull) ? 1 : 0;
            flags[1] = (hits > 8) ? 1 : 0;
        }
    }
}

// ---------------------------------------------------------------- edge sort
__global__ void hist_kernel(const void* __restrict__ ei, int E, const int* __restrict__ flags,
                            int* __restrict__ deg) {
    int e = blockIdx.x * blockDim.x + threadIdx.x;
    if (e >= E) return;
    int d = flags[0] ? (int)((const long long*)ei)[(size_t)E + e]
                     : ((const int*)ei)[(size_t)E + e];
    atomicAdd(&deg[d], 1);
}

__global__ void scan_kernel(const int* __restrict__ deg, int* __restrict__ offs,
                            int* __restrict__ cursor) {
    __shared__ int part[256];
    int tid = threadIdx.x;
    int base = tid * 64;
    int s = 0;
    for (int i = 0; i < 64; ++i) s += deg[base + i];
    part[tid] = s;
    __syncthreads();
    for (int off = 1; off < 256; off <<= 1) {
        int t = (tid >= off) ? part[tid - off] : 0;
        __syncthreads();
        part[tid] += t;
        __syncthreads();
    }
    int run = (tid > 0) ? part[tid - 1] : 0;
    for (int i = 0; i < 64; ++i) {
        int idx = base + i;
        offs[idx] = run;
        cursor[idx] = run;
        run += deg[idx];
    }
    if (tid == 255) offs[NODES] = run;
}

__global__ void scatter_kernel(const void* __restrict__ ei, int E, const int* __restrict__ flags,
                               int* __restrict__ cursor, int* __restrict__ ssrc) {
    int e = blockIdx.x * blockDim.x + threadIdx.x;
    if (e >= E) return;
    int s, d;
    if (flags[0]) {
        const long long* p = (const long long*)ei;
        s = (int)p[e];
        d = (int)p[(size_t)E + e];
    } else {
        const int* p = (const int*)ei;
        s = p[e];
        d = p[(size_t)E + e];
    }
    int pos = atomicAdd(&cursor[d], 1);
    ssrc[pos] = s;
}

// ------------------------------------------- x0 staging + weight prep fused
#define T0 (NODES * K1PAD)
#define S1 (512 * K1PAD)
#define S2 (512 * 256)
__global__ void setup_kernel(const void* __restrict__ pooled, const void* __restrict__ rois,
                             const void* __restrict__ W1, const void* __restrict__ W2,
                             const void* __restrict__ W3, const int* __restrict__ flags,
                             unsigned short* __restrict__ x0p, void* __restrict__ outv,
                             unsigned short* __restrict__ wc1, unsigned short* __restrict__ wc2,
                             unsigned short* __restrict__ wc3) {
    int idx = blockIdx.x * 256 + threadIdx.x;
    bool f32m = flags[1] != 0;
    if (idx < T0) {
        int node = idx / K1PAD;
        int k = idx - node * K1PAD;
        float val = 0.f;
        if (k < 256) {
            val = f32m ? ((const float*)pooled)[(size_t)node * 256 + k]
                       : bf2f(((const unsigned short*)pooled)[(size_t)node * 256 + k]);
        } else if (k < D0) {
            val = f32m ? ((const float*)rois)[(size_t)node * 7 + (k - 256)]
                       : bf2f(((const unsigned short*)rois)[(size_t)node * 7 + (k - 256)]);
        }
        x0p[idx] = f2bf(val);
        if (k < D0) {
            if (f32m) ((float*)outv)[(size_t)node * OUTW + k] = val;
            else      ((unsigned short*)outv)[(size_t)node * OUTW + k] = f2bf(val);
        }
        return;
    }
    idx -= T0;
    if (idx < S1) {
        // layer 1: W1 is [256][526], in=263 padded to 288
        int r = idx / K1PAD;
        int k = idx - r * K1PAD;
        unsigned short val = 0;
        if (k < D0) {
            if (r < 256) {
                float a = f32m ? ((const float*)W1)[(size_t)r * 526 + k]
                               : bf2f(((const unsigned short*)W1)[(size_t)r * 526 + k]);
                val = f2bf(a);
            } else {
                size_t ro = (size_t)(r - 256) * 526;
                float a, b;
                if (f32m) { a = ((const float*)W1)[ro + k]; b = ((const float*)W1)[ro + D0 + k]; }
                else      { a = bf2f(((const unsigned short*)W1)[ro + k]);
                            b = bf2f(((const unsigned short*)W1)[ro + D0 + k]); }
                val = f2bf(b - a);
            }
        }
        wc1[idx] = val;
        return;
    }
    idx -= S1;
    const void* W = (idx < S2) ? W2 : W3;
    unsigned short* wc = (idx < S2) ? wc2 : wc3;
    if (idx >= S2) idx -= S2;
    int r = idx >> 8;
    int k = idx & 255;
    unsigned short val;
    if (r < 256) {
        float a = f32m ? ((const float*)W)[(size_t)r * 512 + k]
                       : bf2f(((const unsigned short*)W)[(size_t)r * 512 + k]);
        val = f2bf(a);
    } else {
        size_t ro = (size_t)(r - 256) * 512;
        float a, b;
        if (f32m) { a = ((const float*)W)[ro + k]; b = ((const float*)W)[ro + 256 + k]; }
        else      { a = bf2f(((const unsigned short*)W)[ro + k]);
                    b = bf2f(((const unsigned short*)W)[ro + 256 + k]); }
        val = f2bf(b - a);
    }
    wc[idx] = val;
}

// ---------------------------------------------------------------- GEMM
// T[M,512] = A[M,K]*Wc[512,K]^T ; cols 0..255 -> u keys, 256..511 -> v (f32)
// wave = 64x64 (acc[4][4]); block 64x256; grid (M/64,2).
template <int K>
__global__ __launch_bounds__(256) void gemm_kernel(const unsigned short* __restrict__ A,
                                                   const unsigned short* __restrict__ Wc,
                                                   unsigned short* __restrict__ u_key,
                                                   float* __restrict__ v_f) {
    int lane = threadIdx.x & 63;
    int wave = threadIdx.x >> 6;
    int row0 = blockIdx.x * 64;
    int col0 = blockIdx.y * 256 + wave * 64;
    int lr = lane & 15;
    int kb = (lane >> 4) * 8;
    const unsigned short* Ap = A + (size_t)(row0 + lr) * K + kb;
    const unsigned short* Wp = Wc + (size_t)(col0 + lr) * K + kb;

    f32x4 acc[4][4];
    #pragma unroll
    for (int i = 0; i < 4; ++i)
        #pragma unroll
        for (int j = 0; j < 4; ++j) acc[i][j] = (f32x4){0.f, 0.f, 0.f, 0.f};

    for (int k0 = 0; k0 < K; k0 += 32) {
        bf16x8 a[4], b[4];
        #pragma unroll
        for (int i = 0; i < 4; ++i) a[i] = *reinterpret_cast<const bf16x8*>(Ap + (size_t)i * 16 * K + k0);
        #pragma unroll
        for (int i = 0; i < 4; ++i) b[i] = *reinterpret_cast<const bf16x8*>(Wp + (size_t)i * 16 * K + k0);
        #pragma unroll
        for (int rb = 0; rb < 4; ++rb)
            #pragma unroll
            for (int cb = 0; cb < 4; ++cb)
                acc[rb][cb] = __builtin_amdgcn_mfma_f32_16x16x32_bf16(a[rb], b[cb], acc[rb][cb], 0, 0, 0);
    }

    bool is_u = (blockIdx.y == 0);
    #pragma unroll
    for (int rb = 0; rb < 4; ++rb) {
        int rbase = row0 + rb * 16 + (lane >> 4) * 4;
        #pragma unroll
        for (int cb = 0; cb < 4; ++cb) {
            int c = col0 + cb * 16 + lr;
            #pragma unroll
            for (int reg = 0; reg < 4; ++reg) {
                float val = acc[rb][cb][reg];
                int r = rbase + reg;
                if (is_u) u_key[(size_t)r * 256 + c] = bf2key(f2bf(val));
                else      v_f[(size_t)r * 256 + (c - 256)] = val;
            }
        }
    }
}

// ---------------------------------------------------------------- combine
// one wave per node; halves own alternate sorted edges and read the full
// 256-ch key row (32 lanes x 16B). Software-pipelined: prefetch next 8 edge
// indices while current 8 row-gathers are in flight. NT on streaming traffic
// (ssrc, v, stores); u gathers stay cached.
#define GATHER8(i0,i1,i2,i3,i4,i5,i6,i7)                                        \
    do {                                                                        \
        u16x8 p0 = U[(size_t)(i0) * 32 + cl], p1 = U[(size_t)(i1) * 32 + cl];   \
        u16x8 p2 = U[(size_t)(i2) * 32 + cl], p3 = U[(size_t)(i3) * 32 + cl];   \
        u16x8 p4 = U[(size_t)(i4) * 32 + cl], p5 = U[(size_t)(i5) * 32 + cl];   \
        u16x8 p6 = U[(size_t)(i6) * 32 + cl], p7 = U[(size_t)(i7) * 32 + cl];   \
        u16x8 q0 = __builtin_elementwise_max(p0, p1);                           \
        u16x8 q1 = __builtin_elementwise_max(p2, p3);                           \
        u16x8 q2 = __builtin_elementwise_max(p4, p5);                           \
        u16x8 q3 = __builtin_elementwise_max(p6, p7);                           \
        mk = __builtin_elementwise_max(mk, __builtin_elementwise_max(           \
                 __builtin_elementwise_max(q0, q1),                             \
                 __builtin_elementwise_max(q2, q3)));                           \
    } while (0)

__global__ __launch_bounds__(256) void combine_kernel(const unsigned short* __restrict__ u_key,
                                                      const float* __restrict__ v_f,
                                                      const void* __restrict__ bias,
                                                      const int* __restrict__ flags,
                                                      const int* __restrict__ offs,
                                                      const int* __restrict__ ssrc,
                                                      unsigned short* __restrict__ x_cur,
                                                      void* __restrict__ outv,
                                                      int col_off) {
    int lane = threadIdx.x & 63;
    int node = blockIdx.x * 4 + (threadIdx.x >> 6);
    int half = lane >> 5;      // 0/1: alternate edges
    int cl = lane & 31;        // 16B chunk of the 512B row
    int s0 = offs[node];
    int s1 = offs[node + 1];
    bool f32m = flags[1] != 0;

    const u16x8* U = (const u16x8*)u_key;   // one row = 32 u16x8 (256 keys)
    u16x8 mk = (u16x8)0;

    int i = s0 + half;
    if (i + 14 < s1) {
        int a0 = __builtin_nontemporal_load(&ssrc[i]);
        int a1 = __builtin_nontemporal_load(&ssrc[i + 2]);
        int a2 = __builtin_nontemporal_load(&ssrc[i + 4]);
        int a3 = __builtin_nontemporal_load(&ssrc[i + 6]);
        int a4 = __builtin_nontemporal_load(&ssrc[i + 8]);
        int a5 = __builtin_nontemporal_load(&ssrc[i + 10]);
        int a6 = __builtin_nontemporal_load(&ssrc[i + 12]);
        int a7 = __builtin_nontemporal_load(&ssrc[i + 14]);
        i += 16;
        while (i + 14 < s1) {
            int b0 = __builtin_nontemporal_load(&ssrc[i]);
            int b1 = __builtin_nontemporal_load(&ssrc[i + 2]);
            int b2 = __builtin_nontemporal_load(&ssrc[i + 4]);
            int b3 = __builtin_nontemporal_load(&ssrc[i + 6]);
            int b4 = __builtin_nontemporal_load(&ssrc[i + 8]);
            int b5 = __builtin_nontemporal_load(&ssrc[i + 10]);
            int b6 = __builtin_nontemporal_load(&ssrc[i + 12]);
            int b7 = __builtin_nontemporal_load(&ssrc[i + 14]);
            GATHER8(a0, a1, a2, a3, a4, a5, a6, a7);
            a0 = b0; a1 = b1; a2 = b2; a3 = b3;
            a4 = b4; a5 = b5; a6 = b6; a7 = b7;
            i += 16;
        }
        GATHER8(a0, a1, a2, a3, a4, a5, a6, a7);
    }
    for (; i + 6 < s1; i += 8) {
        int c0 = __builtin_nontemporal_load(&ssrc[i]);
        int c1 = __builtin_nontemporal_load(&ssrc[i + 2]);
        int c2 = __builtin_nontemporal_load(&ssrc[i + 4]);
        int c3 = __builtin_nontemporal_load(&ssrc[i + 6]);
        u16x8 p0 = U[(size_t)c0 * 32 + cl], p1 = U[(size_t)c1 * 32 + cl];
        u16x8 p2 = U[(size_t)c2 * 32 + cl], p3 = U[(size_t)c3 * 32 + cl];
        mk = __builtin_elementwise_max(mk, __builtin_elementwise_max(
                 __builtin_elementwise_max(p0, p1), __builtin_elementwise_max(p2, p3)));
    }
    for (; i < s1; i += 2) {
        int s = __builtin_nontemporal_load(&ssrc[i]);
        mk = __builtin_elementwise_max(mk, U[(size_t)s * 32 + cl]);
    }

    // merge halves: lanes l and l^32 hold the same 8 channels
    union { u16x8 v; uint4 u; } c1;
    c1.v = mk;
    c1.u.x = __shfl_xor((int)c1.u.x, 32);
    c1.u.y = __shfl_xor((int)c1.u.y, 32);
    c1.u.z = __shfl_xor((int)c1.u.z, 32);
    c1.u.w = __shfl_xor((int)c1.u.w, 32);
    mk = __builtin_elementwise_max(mk, c1.v);

    // epilogue: lane handles 4 channels: ch0 = cl*8 + half*4
    int ch0 = cl * 8 + half * 4;
    float mm[4];
    #pragma unroll
    for (int j = 0; j < 4; ++j) mm[j] = bf2f(key2bf(mk[half * 4 + j]));

    f32x4 v = __builtin_nontemporal_load(
        (const f32x4*)(v_f + (size_t)node * 256 + ch0));
    float bb[4];
    if (f32m) {
        const float* bf = (const float*)bias;
        #pragma unroll
        for (int j = 0; j < 4; ++j) bb[j] = bf[ch0 + j];
    } else {
        const unsigned short* bh = (const unsigned short*)bias;
        #pragma unroll
        for (int j = 0; j < 4; ++j) bb[j] = bf2f(bh[ch0 + j]);
    }
    float r[4];
    bool nz = (s1 > s0);
    #pragma unroll
    for (int j = 0; j < 4; ++j) r[j] = nz ? fmaxf(mm[j] + v[j] + bb[j], 0.f) : 0.f;

    unsigned short h[4];
    #pragma unroll
    for (int j = 0; j < 4; ++j) h[j] = f2bf(r[j]);
    unsigned long long packed =
        (unsigned long long)h[0] | ((unsigned long long)h[1] << 16) |
        ((unsigned long long)h[2] << 32) | ((unsigned long long)h[3] << 48);
    __builtin_nontemporal_store(packed,
        (unsigned long long*)(x_cur + (size_t)node * 256 + ch0));

    size_t ob = (size_t)node * OUTW + col_off + ch0;
    if (f32m) {
        float* of = (float*)outv;
        #pragma unroll
        for (int j = 0; j < 4; ++j) __builtin_nontemporal_store(r[j], of + ob + j);
    } else {
        unsigned short* oh = (unsigned short*)outv;
        #pragma unroll
        for (int j = 0; j < 4; ++j) __builtin_nontemporal_store(h[j], oh + ob + j);
    }
}

// ---------------------------------------------------------------- launch
extern "C" void kernel_launch(void* const* d_in, const int* in_sizes, int n_in,
                              void* d_out, int out_size, void* d_ws, size_t ws_size,
                              hipStream_t stream) {
    const void* rois   = d_in[0];
    const void* pooled = d_in[1];
    const void* ei     = d_in[2];
    const void* W1 = d_in[3];
    const void* b1 = d_in[4];
    const void* W2 = d_in[5];
    const void* b2 = d_in[6];
    const void* W3 = d_in[7];
    const void* b3 = d_in[8];

    const int E = in_sizes[2] / 2;

    char* ws = (char*)d_ws;
    size_t o = 0;
    auto take = [&](size_t bytes) { size_t cur = o; o += (bytes + 255) & ~(size_t)255; return cur; };
    int* flags           = (int*)(ws + take(8));
    int* deg             = (int*)(ws + take(sizeof(int) * NODES));
    int* offs            = (int*)(ws + take(sizeof(int) * (NODES + 1)));
    int* cursor          = (int*)(ws + take(sizeof(int) * NODES));
    int* ssrc            = (int*)(ws + take(sizeof(int) * (size_t)E));
    unsigned short* x0p  = (unsigned short*)(ws + take(2ull * NODES * K1PAD));
    unsigned short* wc1  = (unsigned short*)(ws + take(2ull * 512 * K1PAD));
    unsigned short* wc2  = (unsigned short*)(ws + take(2ull * 512 * 256));
    unsigned short* wc3  = (unsigned short*)(ws + take(2ull * 512 * 256));
    unsigned short* ukey = (unsigned short*)(ws + take(2ull * NODES * 256));
    float*          vf   = (float*)(ws + take(4ull * NODES * 256));
    unsigned short* xcur = (unsigned short*)(ws + take(2ull * NODES * 256));
    (void)ws_size;

    const int eb = (E + 255) / 256;

    detect_zero_kernel<<<NODES / 256, 256, 0, stream>>>(ei, pooled, flags, deg);
    hist_kernel<<<eb, 256, 0, stream>>>(ei, E, flags, deg);
    scan_kernel<<<1, 256, 0, stream>>>(deg, offs, cursor);
    scatter_kernel<<<eb, 256, 0, stream>>>(ei, E, flags, cursor, ssrc);

    setup_kernel<<<(T0 + S1 + 2 * S2) / 256, 256, 0, stream>>>(pooled, rois, W1, W2, W3, flags,
                                                               x0p, d_out, wc1, wc2, wc3);

    // layer 1
    gemm_kernel<K1PAD><<<dim3(NODES / 64, 2), 256, 0, stream>>>(x0p, wc1, ukey, vf);
    combine_kernel<<<NODES / 4, 256, 0, stream>>>(ukey, vf, b1, flags, offs, ssrc, xcur, d_out, D0);

    // layer 2
    gemm_kernel<256><<<dim3(NODES / 64, 2), 256, 0, stream>>>(xcur, wc2, ukey, vf);
    combine_kernel<<<NODES / 4, 256, 0, stream>>>(ukey, vf, b2, flags, offs, ssrc, xcur, d_out, D0 + 256);

    // layer 3
    gemm_kernel<256><<<dim3(NODES / 64, 2), 256, 0, stream>>>(xcur, wc3, ukey, vf);
    combine_kernel<<<NODES / 4, 256, 0, stream>>>(ukey, vf, b3, flags, offs, ssrc, xcur, d_out, D0 + 512);
}